// Round 19
// baseline (103.251 us; speedup 1.0000x reference)
//
#include <hip/hip_runtime.h>
#include <hip/hip_bf16.h>

// Problem dims (fixed by reference setup_inputs)
#define NQ 8
#define NK 1024
#define ND 64
#define NH 1024
#define NB 8
#define NT 8192

typedef float  vfloat4 __attribute__((ext_vector_type(4)));
typedef float  vfloat2 __attribute__((ext_vector_type(2)));
typedef float  f32x4   __attribute__((ext_vector_type(4)));
typedef short  short8  __attribute__((ext_vector_type(8)));

// HW packed f32->bf16 (RNE). Plain VALU asm (R9-R16 verified).
__device__ __forceinline__ unsigned cvt_pk_bf16(float lo, float hi) {
    unsigned r;
    asm("v_cvt_pk_bf16_f32 %0, %1, %2" : "=v"(r) : "v"(lo), "v"(hi));
    return r;
}

// ------------- Kernel 0: convert cb and W to bf16 (exact R11/R16) ----------
__global__ __launch_bounds__(256) void to_bf16(const float* __restrict__ cb,
                                               const float* __restrict__ W,
                                               uint4* __restrict__ cbh,
                                               uint4* __restrict__ Wh) {
    int half = blockIdx.x >> 8;
    int i    = ((blockIdx.x & 255) << 8) + threadIdx.x;  // 0..65535
    const float4* src = (const float4*)(half ? W : cb);
    float4 a = src[i * 2], b = src[i * 2 + 1];
    uint4 o;
    o.x = cvt_pk_bf16(a.x, a.y);
    o.y = cvt_pk_bf16(a.z, a.w);
    o.z = cvt_pk_bf16(b.x, b.y);
    o.w = cvt_pk_bf16(b.z, b.w);
    (half ? Wh : cbh)[i] = o;
}

// ------------- Kernel 1: build projected codebook via MFMA (exact R16) -----
// Pt rows 8h-interleaved: uint4 row (hg8, q, k) holds h = hg8*8 + 0..7;
// lane grp writes its uint2 (4h) into word (hg&1).
__global__ __launch_bounds__(256) void build_Pt(const short* __restrict__ cbh,
                                                const short* __restrict__ Wh,
                                                const float* __restrict__ bias,
                                                uint2* __restrict__ Pt2) {
    int q    = blockIdx.x >> 8;        // 8
    int rest = blockIdx.x & 255;
    int hb   = rest >> 4;              // 16 h-blocks of 64
    int kb   = rest & 15;              // 16 k-blocks of 64
    int wave = threadIdx.x >> 6, lane = threadIdx.x & 63;
    int h_tile = hb * 64 + wave * 16;
    int row16 = lane & 15, grp = lane >> 4;  // grp 0..3

    short8 afrag[2];
    const short* wrow = Wh + ((size_t)q * NH + h_tile + row16) * ND + grp * 8;
    afrag[0] = *(const short8*)(wrow);
    afrag[1] = *(const short8*)(wrow + 32);

    float bvals[4];
#pragma unroll
    for (int r = 0; r < 4; ++r) bvals[r] = bias[q * NH + h_tile + grp * 4 + r];

    int k0 = kb * 64;
    const short* cbase = cbh + ((size_t)q * NK + k0 + row16) * ND + grp * 8;
    int hg = (h_tile >> 2) + grp;      // 4h-group index 0..255

#pragma unroll
    for (int t = 0; t < 4; ++t) {
        const short* crow = cbase + (size_t)t * 16 * ND;
        short8 b0 = *(const short8*)(crow);
        short8 b1 = *(const short8*)(crow + 32);
        f32x4 acc = {0.f, 0.f, 0.f, 0.f};
        acc = __builtin_amdgcn_mfma_f32_16x16x32_bf16(afrag[0], b0, acc, 0, 0, 0);
        acc = __builtin_amdgcn_mfma_f32_16x16x32_bf16(afrag[1], b1, acc, 0, 0, 0);
        int k = k0 + t * 16 + row16;
        uint2 pk;
        pk.x = cvt_pk_bf16(acc[0] + bvals[0], acc[1] + bvals[1]);
        pk.y = cvt_pk_bf16(acc[2] + bvals[2], acc[3] + bvals[3]);
        Pt2[((((size_t)(hg >> 1) * NQ) + q) * NK + k) * 2 + (hg & 1)] = pk;
    }
}

// ------------- Kernel 2: hybrid gather — 6q from LDS, 2q from L2 -----------
// out[b,h,t] = sum_q P[q, codes[q,b,t], h]   (bias folded into P)
// R18 analysis: LDS pipe saturated (4096 random b128/CU x ~30cyc ~= 51us)
// while VMEM sits idle between store bursts. LDS and VMEM are separate pipes
// (m114) -> split the q dimension: q=0..5 staged in 96KB LDS (3072
// wave-instr/CU ~= 38us), q=6..7 gathered straight from Pt in L2 (1024
// wave-instr/CU, ~1MB hot/XCD resident, sector traffic ~1.07GB ~= 32us at
// L2 BW) — both under the old 51us LDS lane. Global gathers issued before
// the LDS loop per tt so they're in flight during LDS reads.
__global__ __launch_bounds__(1024) void gather_hyb(const int* __restrict__ codes,
                                                   const uint4* __restrict__ Pt4,
                                                   float* __restrict__ out) {
    int th  = blockIdx.x & 1;
    int hg8 = blockIdx.x >> 1;     // 0..127
    int tid = threadIdx.x;

    __shared__ uint4 Pl[6 * NK];   // 96 KB: q = 0..5 slices
    const uint4* src = Pt4 + (size_t)hg8 * NQ * NK;
#pragma unroll
    for (int i = 0; i < 6; ++i) Pl[tid + i * 1024] = src[tid + i * 1024];
    __syncthreads();

    const uint4* bq6 = src + 6 * NK;
    const uint4* bq7 = src + 7 * NK;

    int h0 = hg8 * 8;
    int t0 = th * (NT / 2) + tid * 4;

#pragma unroll 1
    for (int b = 0; b < NB; ++b) {
        vfloat2 acc[4][4];  // [tt][p]: (h 2p exact, h 2p+1 + low-bit noise)
#pragma unroll
        for (int tt = 0; tt < 4; ++tt)
#pragma unroll
            for (int p = 0; p < 4; ++p) acc[tt][p] = (vfloat2){0.f, 0.f};

        // codes for all 8 q (int4 each)
        int4 cc[8];
#pragma unroll
        for (int q = 0; q < NQ; ++q)
            cc[q] = *(const int4*)(codes + ((size_t)q * NB + b) * NT + t0);

#pragma unroll
        for (int tt = 0; tt < 4; ++tt) {
            // issue the two L2 gathers first (in flight during LDS reads)
            int c6 = (tt == 0) ? cc[6].x : (tt == 1) ? cc[6].y : (tt == 2) ? cc[6].z : cc[6].w;
            int c7 = (tt == 0) ? cc[7].x : (tt == 1) ? cc[7].y : (tt == 2) ? cc[7].z : cc[7].w;
            uint4 g6 = bq6[c6];   // global_load_dwordx4 (XCD L2)
            uint4 g7 = bq7[c7];
#pragma unroll
            for (int q = 0; q < 6; ++q) {
                int c = (tt == 0) ? cc[q].x : (tt == 1) ? cc[q].y : (tt == 2) ? cc[q].z : cc[q].w;
                uint4 v = Pl[q * NK + c];   // ds_read_b128
                acc[tt][0] += (vfloat2){__uint_as_float(v.x << 16), __uint_as_float(v.x)};
                acc[tt][1] += (vfloat2){__uint_as_float(v.y << 16), __uint_as_float(v.y)};
                acc[tt][2] += (vfloat2){__uint_as_float(v.z << 16), __uint_as_float(v.z)};
                acc[tt][3] += (vfloat2){__uint_as_float(v.w << 16), __uint_as_float(v.w)};
            }
            acc[tt][0] += (vfloat2){__uint_as_float(g6.x << 16), __uint_as_float(g6.x)};
            acc[tt][1] += (vfloat2){__uint_as_float(g6.y << 16), __uint_as_float(g6.y)};
            acc[tt][2] += (vfloat2){__uint_as_float(g6.z << 16), __uint_as_float(g6.z)};
            acc[tt][3] += (vfloat2){__uint_as_float(g6.w << 16), __uint_as_float(g6.w)};
            acc[tt][0] += (vfloat2){__uint_as_float(g7.x << 16), __uint_as_float(g7.x)};
            acc[tt][1] += (vfloat2){__uint_as_float(g7.y << 16), __uint_as_float(g7.y)};
            acc[tt][2] += (vfloat2){__uint_as_float(g7.z << 16), __uint_as_float(g7.z)};
            acc[tt][3] += (vfloat2){__uint_as_float(g7.w << 16), __uint_as_float(g7.w)};
        }

#pragma unroll
        for (int hh = 0; hh < 8; ++hh) {
            vfloat4 o;
            o[0] = acc[0][hh >> 1][hh & 1];
            o[1] = acc[1][hh >> 1][hh & 1];
            o[2] = acc[2][hh >> 1][hh & 1];
            o[3] = acc[3][hh >> 1][hh & 1];
            vfloat4* dstp = (vfloat4*)(out + ((size_t)b * NH + (h0 + hh)) * NT + t0);
            __builtin_nontemporal_store(o, dstp);
        }
    }
}

extern "C" void kernel_launch(void* const* d_in, const int* in_sizes, int n_in,
                              void* d_out, int out_size, void* d_ws, size_t ws_size,
                              hipStream_t stream) {
    const int*   codes = (const int*)d_in[0];    // [Q,B,T] int32
    const float* cb    = (const float*)d_in[1];  // [Q,K,D] f32
    const float* W     = (const float*)d_in[2];  // [Q,H,D] f32
    const float* bias  = (const float*)d_in[3];  // [Q,H] f32
    float*       out   = (float*)d_out;          // [B,H,T] f32

    uint2* Pt2 = (uint2*)d_ws;                          // 16 MB (8h uint4 rows)
    uint4* cbh = (uint4*)((char*)d_ws + (16u << 20));   // 1 MB bf16
    uint4* Wh  = (uint4*)((char*)d_ws + (17u << 20));   // 1 MB bf16

    to_bf16<<<512, 256, 0, stream>>>(cb, W, cbh, Wh);
    build_Pt<<<2048, 256, 0, stream>>>((const short*)cbh, (const short*)Wh, bias, Pt2);
    gather_hyb<<<256, 1024, 0, stream>>>(codes, (const uint4*)Pt2, out);
}

// Round 20
// 76.802 us; speedup vs baseline: 1.3444x; 1.3444x over previous
//
#include <hip/hip_runtime.h>
#include <hip/hip_bf16.h>

// Problem dims (fixed by reference setup_inputs)
#define NQ 8
#define NK 1024
#define ND 64
#define NH 1024
#define NB 8
#define NT 8192

typedef float  vfloat4 __attribute__((ext_vector_type(4)));
typedef float  vfloat2 __attribute__((ext_vector_type(2)));
typedef float  f32x4   __attribute__((ext_vector_type(4)));
typedef short  short8  __attribute__((ext_vector_type(8)));

// HW packed f32->bf16 (RNE). Plain VALU asm (R9-R16 verified).
__device__ __forceinline__ unsigned cvt_pk_bf16(float lo, float hi) {
    unsigned r;
    asm("v_cvt_pk_bf16_f32 %0, %1, %2" : "=v"(r) : "v"(lo), "v"(hi));
    return r;
}

// ------------- Kernel 0: prepass — convert cb/W to bf16 + pack codes -------
// blocks 0..255: cb; 256..511: W (exact R16 to_bf16). blocks 512..575: pack
// codes [q][b][t] int32 -> [b][t] row of 8 x uint16 (16B per position).
__global__ __launch_bounds__(256) void prepass(const float* __restrict__ cb,
                                               const float* __restrict__ W,
                                               const int* __restrict__ codes,
                                               uint4* __restrict__ cbh,
                                               uint4* __restrict__ Wh,
                                               uint4* __restrict__ cpk) {
    int blk = blockIdx.x;
    if (blk < 512) {
        int half = blk >> 8;
        int i    = ((blk & 255) << 8) + threadIdx.x;  // 0..65535
        const float4* src = (const float4*)(half ? W : cb);
        float4 a = src[i * 2], b = src[i * 2 + 1];
        uint4 o;
        o.x = cvt_pk_bf16(a.x, a.y);
        o.y = cvt_pk_bf16(a.z, a.w);
        o.z = cvt_pk_bf16(b.x, b.y);
        o.w = cvt_pk_bf16(b.z, b.w);
        (half ? Wh : cbh)[i] = o;
    } else {
        // 64 blocks x 256 thr x 4 positions = 65536 (b,t) pairs
        int idx = ((blk - 512) * 256 + threadIdx.x) * 4;  // flat b*NT+t base
        int4 c[NQ];
#pragma unroll
        for (int q = 0; q < NQ; ++q)
            c[q] = *(const int4*)(codes + (size_t)q * NB * NT + idx);
#pragma unroll
        for (int tt = 0; tt < 4; ++tt) {
            int cq[NQ];
            cq[0] = (tt==0)?c[0].x:(tt==1)?c[0].y:(tt==2)?c[0].z:c[0].w;
            cq[1] = (tt==0)?c[1].x:(tt==1)?c[1].y:(tt==2)?c[1].z:c[1].w;
            cq[2] = (tt==0)?c[2].x:(tt==1)?c[2].y:(tt==2)?c[2].z:c[2].w;
            cq[3] = (tt==0)?c[3].x:(tt==1)?c[3].y:(tt==2)?c[3].z:c[3].w;
            cq[4] = (tt==0)?c[4].x:(tt==1)?c[4].y:(tt==2)?c[4].z:c[4].w;
            cq[5] = (tt==0)?c[5].x:(tt==1)?c[5].y:(tt==2)?c[5].z:c[5].w;
            cq[6] = (tt==0)?c[6].x:(tt==1)?c[6].y:(tt==2)?c[6].z:c[6].w;
            cq[7] = (tt==0)?c[7].x:(tt==1)?c[7].y:(tt==2)?c[7].z:c[7].w;
            uint4 o;
            o.x = (unsigned)cq[0] | ((unsigned)cq[1] << 16);
            o.y = (unsigned)cq[2] | ((unsigned)cq[3] << 16);
            o.z = (unsigned)cq[4] | ((unsigned)cq[5] << 16);
            o.w = (unsigned)cq[6] | ((unsigned)cq[7] << 16);
            cpk[idx + tt] = o;
        }
    }
}

// ------------- Kernel 1: build projected codebook via MFMA (exact R16) -----
// Pt rows 8h-interleaved: uint4 row (hg8, q, k) holds h = hg8*8 + 0..7;
// lane grp writes its uint2 (4h) into word (hg&1).
__global__ __launch_bounds__(256) void build_Pt(const short* __restrict__ cbh,
                                                const short* __restrict__ Wh,
                                                const float* __restrict__ bias,
                                                uint2* __restrict__ Pt2) {
    int q    = blockIdx.x >> 8;        // 8
    int rest = blockIdx.x & 255;
    int hb   = rest >> 4;              // 16 h-blocks of 64
    int kb   = rest & 15;              // 16 k-blocks of 64
    int wave = threadIdx.x >> 6, lane = threadIdx.x & 63;
    int h_tile = hb * 64 + wave * 16;
    int row16 = lane & 15, grp = lane >> 4;  // grp 0..3

    short8 afrag[2];
    const short* wrow = Wh + ((size_t)q * NH + h_tile + row16) * ND + grp * 8;
    afrag[0] = *(const short8*)(wrow);
    afrag[1] = *(const short8*)(wrow + 32);

    float bvals[4];
#pragma unroll
    for (int r = 0; r < 4; ++r) bvals[r] = bias[q * NH + h_tile + grp * 4 + r];

    int k0 = kb * 64;
    const short* cbase = cbh + ((size_t)q * NK + k0 + row16) * ND + grp * 8;
    int hg = (h_tile >> 2) + grp;      // 4h-group index 0..255

#pragma unroll
    for (int t = 0; t < 4; ++t) {
        const short* crow = cbase + (size_t)t * 16 * ND;
        short8 b0 = *(const short8*)(crow);
        short8 b1 = *(const short8*)(crow + 32);
        f32x4 acc = {0.f, 0.f, 0.f, 0.f};
        acc = __builtin_amdgcn_mfma_f32_16x16x32_bf16(afrag[0], b0, acc, 0, 0, 0);
        acc = __builtin_amdgcn_mfma_f32_16x16x32_bf16(afrag[1], b1, acc, 0, 0, 0);
        int k = k0 + t * 16 + row16;
        uint2 pk;
        pk.x = cvt_pk_bf16(acc[0] + bvals[0], acc[1] + bvals[1]);
        pk.y = cvt_pk_bf16(acc[2] + bvals[2], acc[3] + bvals[3]);
        Pt2[((((size_t)(hg >> 1) * NQ) + q) * NK + k) * 2 + (hg & 1)] = pk;
    }
}

// ------------- Kernel 2: gather-sum, 8h per ds_read_b128 (R16 body) --------
// out[b,h,t] = sum_q P[q, codes[q,b,t], h]   (bias folded into P)
// LDS is the home for P (R17/R19: random 16B gathers via VMEM/L2 cost ~76cyc
// sector-amplified; LDS random b128 ~30cyc = statistical conflict limit).
// Codes come from the packed [b][t] uint16x8 rows: 4 contiguous 16B loads
// per b-iter instead of 8 scattered int4 streams.
__global__ __launch_bounds__(1024) void gather_sum8(const uint4* __restrict__ cpk,
                                                    const uint4* __restrict__ Pt4,
                                                    float* __restrict__ out) {
    int th  = blockIdx.x & 1;
    int hg8 = blockIdx.x >> 1;     // 0..127
    int tid = threadIdx.x;

    __shared__ uint4 Pl[NQ * NK];  // 128 KB
    const uint4* src = Pt4 + (size_t)hg8 * NQ * NK;
#pragma unroll
    for (int i = 0; i < 8; ++i) Pl[tid + i * 1024] = src[tid + i * 1024];
    __syncthreads();

    int h0 = hg8 * 8;
    int t0 = th * (NT / 2) + tid * 4;

#pragma unroll 1
    for (int b = 0; b < NB; ++b) {
        vfloat2 acc[4][4];  // [tt][p]: (h 2p exact, h 2p+1 + low-bit noise)
#pragma unroll
        for (int tt = 0; tt < 4; ++tt)
#pragma unroll
            for (int p = 0; p < 4; ++p) acc[tt][p] = (vfloat2){0.f, 0.f};

#pragma unroll
        for (int tt = 0; tt < 4; ++tt) {
            uint4 w = cpk[(size_t)b * NT + t0 + tt];  // 8 codes, 2 per word
#pragma unroll
            for (int q = 0; q < NQ; ++q) {
                unsigned word = (q < 2) ? w.x : (q < 4) ? w.y : (q < 6) ? w.z : w.w;
                int c = (q & 1) ? (int)(word >> 16) : (int)(word & 0xffffu);
                uint4 v = Pl[q * NK + c];   // ds_read_b128: 8 bf16 h-values
                acc[tt][0] += (vfloat2){__uint_as_float(v.x << 16), __uint_as_float(v.x)};
                acc[tt][1] += (vfloat2){__uint_as_float(v.y << 16), __uint_as_float(v.y)};
                acc[tt][2] += (vfloat2){__uint_as_float(v.z << 16), __uint_as_float(v.z)};
                acc[tt][3] += (vfloat2){__uint_as_float(v.w << 16), __uint_as_float(v.w)};
            }
        }
#pragma unroll
        for (int hh = 0; hh < 8; ++hh) {
            vfloat4 o;
            o[0] = acc[0][hh >> 1][hh & 1];
            o[1] = acc[1][hh >> 1][hh & 1];
            o[2] = acc[2][hh >> 1][hh & 1];
            o[3] = acc[3][hh >> 1][hh & 1];
            vfloat4* dstp = (vfloat4*)(out + ((size_t)b * NH + (h0 + hh)) * NT + t0);
            __builtin_nontemporal_store(o, dstp);
        }
    }
}

extern "C" void kernel_launch(void* const* d_in, const int* in_sizes, int n_in,
                              void* d_out, int out_size, void* d_ws, size_t ws_size,
                              hipStream_t stream) {
    const int*   codes = (const int*)d_in[0];    // [Q,B,T] int32
    const float* cb    = (const float*)d_in[1];  // [Q,K,D] f32
    const float* W     = (const float*)d_in[2];  // [Q,H,D] f32
    const float* bias  = (const float*)d_in[3];  // [Q,H] f32
    float*       out   = (float*)d_out;          // [B,H,T] f32

    uint2* Pt2 = (uint2*)d_ws;                          // 16 MB (8h uint4 rows)
    uint4* cbh = (uint4*)((char*)d_ws + (16u << 20));   // 1 MB bf16
    uint4* Wh  = (uint4*)((char*)d_ws + (17u << 20));   // 1 MB bf16
    uint4* cpk = (uint4*)((char*)d_ws + (18u << 20));   // 1 MB packed codes

    prepass<<<576, 256, 0, stream>>>(cb, W, codes, cbh, Wh, cpk);
    build_Pt<<<2048, 256, 0, stream>>>((const short*)cbh, (const short*)Wh, bias, Pt2);
    gather_sum8<<<256, 1024, 0, stream>>>(cpk, (const uint4*)Pt2, out);
}

// Round 21
// 74.285 us; speedup vs baseline: 1.3899x; 1.0339x over previous
//
#include <hip/hip_runtime.h>
#include <hip/hip_bf16.h>

// Problem dims (fixed by reference setup_inputs)
#define NQ 8
#define NK 1024
#define ND 64
#define NH 1024
#define NB 8
#define NT 8192

typedef float  vfloat4 __attribute__((ext_vector_type(4)));
typedef float  vfloat2 __attribute__((ext_vector_type(2)));
typedef float  f32x4   __attribute__((ext_vector_type(4)));
typedef short  short8  __attribute__((ext_vector_type(8)));

// HW packed f32->bf16 (RNE). Plain VALU asm (R9-R16 verified).
__device__ __forceinline__ unsigned cvt_pk_bf16(float lo, float hi) {
    unsigned r;
    asm("v_cvt_pk_bf16_f32 %0, %1, %2" : "=v"(r) : "v"(lo), "v"(hi));
    return r;
}

// ------------- Kernel 0: convert cb and W to bf16 (exact R11) --------------
__global__ __launch_bounds__(256) void to_bf16(const float* __restrict__ cb,
                                               const float* __restrict__ W,
                                               uint4* __restrict__ cbh,
                                               uint4* __restrict__ Wh) {
    int half = blockIdx.x >> 8;
    int i    = ((blockIdx.x & 255) << 8) + threadIdx.x;  // 0..65535
    const float4* src = (const float4*)(half ? W : cb);
    float4 a = src[i * 2], b = src[i * 2 + 1];
    uint4 o;
    o.x = cvt_pk_bf16(a.x, a.y);
    o.y = cvt_pk_bf16(a.z, a.w);
    o.z = cvt_pk_bf16(b.x, b.y);
    o.w = cvt_pk_bf16(b.z, b.w);
    (half ? Wh : cbh)[i] = o;
}

// ------------- Kernel 1: build projected codebook via MFMA (R11 body) ------
// Pt rows 8h-interleaved: uint4 row = (hg8, q, k) holds h = hg8*8 + 0..7;
// lane grp writes its uint2 (4h) into word (hg&1) of that row.
__global__ __launch_bounds__(256) void build_Pt(const short* __restrict__ cbh,
                                                const short* __restrict__ Wh,
                                                const float* __restrict__ bias,
                                                uint2* __restrict__ Pt2) {
    int q    = blockIdx.x >> 8;        // 8
    int rest = blockIdx.x & 255;
    int hb   = rest >> 4;              // 16 h-blocks of 64
    int kb   = rest & 15;              // 16 k-blocks of 64
    int wave = threadIdx.x >> 6, lane = threadIdx.x & 63;
    int h_tile = hb * 64 + wave * 16;
    int row16 = lane & 15, grp = lane >> 4;  // grp 0..3

    short8 afrag[2];
    const short* wrow = Wh + ((size_t)q * NH + h_tile + row16) * ND + grp * 8;
    afrag[0] = *(const short8*)(wrow);
    afrag[1] = *(const short8*)(wrow + 32);

    float bvals[4];
#pragma unroll
    for (int r = 0; r < 4; ++r) bvals[r] = bias[q * NH + h_tile + grp * 4 + r];

    int k0 = kb * 64;
    const short* cbase = cbh + ((size_t)q * NK + k0 + row16) * ND + grp * 8;
    int hg = (h_tile >> 2) + grp;      // 4h-group index 0..255

#pragma unroll
    for (int t = 0; t < 4; ++t) {
        const short* crow = cbase + (size_t)t * 16 * ND;
        short8 b0 = *(const short8*)(crow);
        short8 b1 = *(const short8*)(crow + 32);
        f32x4 acc = {0.f, 0.f, 0.f, 0.f};
        acc = __builtin_amdgcn_mfma_f32_16x16x32_bf16(afrag[0], b0, acc, 0, 0, 0);
        acc = __builtin_amdgcn_mfma_f32_16x16x32_bf16(afrag[1], b1, acc, 0, 0, 0);
        int k = k0 + t * 16 + row16;
        uint2 pk;
        pk.x = cvt_pk_bf16(acc[0] + bvals[0], acc[1] + bvals[1]);
        pk.y = cvt_pk_bf16(acc[2] + bvals[2], acc[3] + bvals[3]);
        // 8h-interleaved: uint4 row (hg>>1, q, k), word hg&1
        Pt2[((((size_t)(hg >> 1) * NQ) + q) * NK + k) * 2 + (hg & 1)] = pk;
    }
}

// ------------- Kernel 2: gather-sum, 8h per ds_read_b128 -------------------
// out[b,h,t] = sum_q P[q, codes[q,b,t], h]   (bias folded into P)
// LDS is the home for P: random ds_read_b128 runs ~30cyc/wave-instr
// (statistical bank-conflict limit, data-random addresses); VMEM/L2 random
// 16B gathers cost ~76cyc from 128B-sector amplification (R17/R19). One b128
// read serves 8 h. 128KB LDS slice [q][k] -> uint4 of 8 bf16 h. Grid 256 =
// 128 hg8 x 2 t-halves, 1024 thr. Odd-h lanes carry <2^-8 relative low-bit
// noise (accepted since R12). Coalesced nt float4 stores (39us write floor
// hides under the LDS stream).
__global__ __launch_bounds__(1024) void gather_sum8(const int* __restrict__ codes,
                                                    const uint4* __restrict__ Pt4,
                                                    float* __restrict__ out) {
    int th  = blockIdx.x & 1;
    int hg8 = blockIdx.x >> 1;     // 0..127
    int tid = threadIdx.x;

    __shared__ uint4 Pl[NQ * NK];  // 128 KB
    const uint4* src = Pt4 + (size_t)hg8 * NQ * NK;
#pragma unroll
    for (int i = 0; i < 8; ++i) Pl[tid + i * 1024] = src[tid + i * 1024];
    __syncthreads();

    int h0 = hg8 * 8;
    int t0 = th * (NT / 2) + tid * 4;

#pragma unroll 1
    for (int b = 0; b < NB; ++b) {
        // acc[tt][p]: vfloat2 = (h 2p exact, h 2p+1 + low-bit noise)
        vfloat2 acc[4][4];
#pragma unroll
        for (int tt = 0; tt < 4; ++tt)
#pragma unroll
            for (int p = 0; p < 4; ++p) acc[tt][p] = (vfloat2){0.f, 0.f};

#pragma unroll
        for (int q = 0; q < NQ; ++q) {
            int4 cc = *(const int4*)(codes + ((size_t)q * NB + b) * NT + t0);
#pragma unroll
            for (int tt = 0; tt < 4; ++tt) {
                int c = (tt == 0) ? cc.x : (tt == 1) ? cc.y : (tt == 2) ? cc.z : cc.w;
                uint4 v = Pl[q * NK + c];   // ds_read_b128: 8 bf16 h-values
                acc[tt][0] += (vfloat2){__uint_as_float(v.x << 16), __uint_as_float(v.x)};
                acc[tt][1] += (vfloat2){__uint_as_float(v.y << 16), __uint_as_float(v.y)};
                acc[tt][2] += (vfloat2){__uint_as_float(v.z << 16), __uint_as_float(v.z)};
                acc[tt][3] += (vfloat2){__uint_as_float(v.w << 16), __uint_as_float(v.w)};
            }
        }
#pragma unroll
        for (int hh = 0; hh < 8; ++hh) {
            vfloat4 o;
            o[0] = acc[0][hh >> 1][hh & 1];
            o[1] = acc[1][hh >> 1][hh & 1];
            o[2] = acc[2][hh >> 1][hh & 1];
            o[3] = acc[3][hh >> 1][hh & 1];
            vfloat4* dstp = (vfloat4*)(out + ((size_t)b * NH + (h0 + hh)) * NT + t0);
            __builtin_nontemporal_store(o, dstp);
        }
    }
}

extern "C" void kernel_launch(void* const* d_in, const int* in_sizes, int n_in,
                              void* d_out, int out_size, void* d_ws, size_t ws_size,
                              hipStream_t stream) {
    const int*   codes = (const int*)d_in[0];    // [Q,B,T] int32
    const float* cb    = (const float*)d_in[1];  // [Q,K,D] f32
    const float* W     = (const float*)d_in[2];  // [Q,H,D] f32
    const float* bias  = (const float*)d_in[3];  // [Q,H] f32
    float*       out   = (float*)d_out;          // [B,H,T] f32

    uint2* Pt2 = (uint2*)d_ws;                          // 16 MB (8h uint4 rows)
    uint4* cbh = (uint4*)((char*)d_ws + (16u << 20));   // 1 MB bf16
    uint4* Wh  = (uint4*)((char*)d_ws + (17u << 20));   // 1 MB bf16

    to_bf16<<<512, 256, 0, stream>>>(cb, W, cbh, Wh);
    build_Pt<<<2048, 256, 0, stream>>>((const short*)cbh, (const short*)Wh, bias, Pt2);
    gather_sum8<<<256, 1024, 0, stream>>>(codes, (const uint4*)Pt2, out);
}